// Round 18
// baseline (1213.479 us; speedup 1.0000x reference)
//
#include <hip/hip_runtime.h>
#include <stdint.h>

#define TT 16384
#define HH 4096

typedef uint8_t u8;
typedef uint32_t u32;
typedef __attribute__((ext_vector_type(16))) float f32x16;
typedef __attribute__((ext_vector_type(8))) int i32x8;

// ---- fp8 e4m3 (OCP) pack: 4 floats -> 4 bytes, RNE, saturating ----
__device__ __forceinline__ u32 cvt4_fp8(float a, float b, float c, float d) {
  u32 v = 0;
  v = __builtin_amdgcn_cvt_pk_fp8_f32(a, b, v, false);  // low word
  v = __builtin_amdgcn_cvt_pk_fp8_f32(c, d, v, true);   // high word
  return v;
}

__device__ __forceinline__ void gl_lds16(const void* g, void* l) {
  __builtin_amdgcn_global_load_lds(
      (const __attribute__((address_space(1))) void*)g,
      (__attribute__((address_space(3))) void*)l, 16, 0, 0);
}

__device__ __forceinline__ i32x8 ld32B(const u8* p0, const u8* p1) {
  const uint4 a = *(const uint4*)p0;
  const uint4 b = *(const uint4*)p1;
  i32x8 r;
  r[0] = (int)a.x; r[1] = (int)a.y; r[2] = (int)a.z; r[3] = (int)a.w;
  r[4] = (int)b.x; r[5] = (int)b.y; r[6] = (int)b.z; r[7] = (int)b.w;
  return r;
}

// ---- weight quantize + transpose: w[K][N] fp32 (on fp8 grid) -> wq[N][K] fp8 (plain)
__global__ __launch_bounds__(256) void kwquant(const float* __restrict__ w,
                                               u8* __restrict__ wq) {
  __shared__ __align__(16) u8 tile[64][68];
  const int n0 = blockIdx.x * 64;
  const int k0 = blockIdx.y * 64;
  const int t = threadIdx.x;
  const int tr = t >> 4, tc = t & 15;
#pragma unroll
  for (int p = 0; p < 4; ++p) {
    const int kl = p * 16 + tr;
    const float4 v = *(const float4*)(w + (size_t)(k0 + kl) * HH + n0 + tc * 4);
    const u32 pk = cvt4_fp8(v.x, v.y, v.z, v.w);
    tile[tc * 4 + 0][kl] = (u8)(pk);
    tile[tc * 4 + 1][kl] = (u8)(pk >> 8);
    tile[tc * 4 + 2][kl] = (u8)(pk >> 16);
    tile[tc * 4 + 3][kl] = (u8)(pk >> 24);
  }
  __syncthreads();
  const int jr = t >> 2;
  const int kc = (t & 3) * 16;
  uint4 ov;
  ov.x = *(const u32*)&tile[jr][kc + 0];
  ov.y = *(const u32*)&tile[jr][kc + 4];
  ov.z = *(const u32*)&tile[jr][kc + 8];
  ov.w = *(const u32*)&tile[jr][kc + 12];
  *(uint4*)(wq + (size_t)(n0 + jr) * HH + k0 + kc) = ov;
}

__device__ __forceinline__ float wred_sum(float v) {
#pragma unroll
  for (int o = 32; o; o >>= 1) v += __shfl_down(v, o, 64);
  return v;
}
__device__ __forceinline__ float wred_max(float v) {
#pragma unroll
  for (int o = 32; o; o >>= 1) v = fmaxf(v, __shfl_down(v, o, 64));
  return v;
}

// MODE 0: src=x, write resid=sqrt(x), quantize rmsnorm(x,nw) -> qout,sout
// MODE 1: src=resid, quantize rmsnorm(resid,nw) -> qout,sout
// MODE 2: src=resid, write y=rmsnorm(resid,nw) fp32 -> yout
template <int MODE>
__global__ __launch_bounds__(256) void knorm(const float* __restrict__ src,
                                             const float* __restrict__ nw,
                                             float* __restrict__ resid_out,
                                             u8* __restrict__ qout,
                                             float* __restrict__ sout,
                                             float* __restrict__ yout) {
  __shared__ float red[4];
  __shared__ float redm[4];
  const int row = blockIdx.x;
  const int t = threadIdx.x;
  const int lane = t & 63, wid = t >> 6;
  const float* rp = src + (size_t)row * HH;

  float4 xv[4];
  float ssq = 0.f;
#pragma unroll
  for (int p = 0; p < 4; ++p) {
    xv[p] = *((const float4*)rp + p * 256 + t);
    ssq += xv[p].x * xv[p].x;
    ssq += xv[p].y * xv[p].y;
    ssq += xv[p].z * xv[p].z;
    ssq += xv[p].w * xv[p].w;
  }
  if (MODE == 0) {
    float* rr = resid_out + (size_t)row * HH;
#pragma unroll
    for (int p = 0; p < 4; ++p) {
      float4 r4;
      r4.x = sqrtf(xv[p].x); r4.y = sqrtf(xv[p].y);
      r4.z = sqrtf(xv[p].z); r4.w = sqrtf(xv[p].w);
      *((float4*)rr + p * 256 + t) = r4;
    }
  }
  ssq = wred_sum(ssq);
  if (lane == 0) red[wid] = ssq;
  __syncthreads();
  const float ms = (((red[0] + red[1]) + red[2]) + red[3]) * (1.0f / HH);
  const float inv = 1.0f / sqrtf(ms + 1e-6f);

  float y[16];
  float amax = 0.f;
#pragma unroll
  for (int p = 0; p < 4; ++p) {
    const float4 wv = *((const float4*)nw + p * 256 + t);
    y[p * 4 + 0] = (xv[p].x * inv) * wv.x;
    y[p * 4 + 1] = (xv[p].y * inv) * wv.y;
    y[p * 4 + 2] = (xv[p].z * inv) * wv.z;
    y[p * 4 + 3] = (xv[p].w * inv) * wv.w;
    amax = fmaxf(amax, fabsf(y[p * 4 + 0]));
    amax = fmaxf(amax, fabsf(y[p * 4 + 1]));
    amax = fmaxf(amax, fabsf(y[p * 4 + 2]));
    amax = fmaxf(amax, fabsf(y[p * 4 + 3]));
  }

  if (MODE == 2) {
    float* yp = yout + (size_t)row * HH;
#pragma unroll
    for (int p = 0; p < 4; ++p) {
      float4 o;
      o.x = y[p * 4 + 0]; o.y = y[p * 4 + 1];
      o.z = y[p * 4 + 2]; o.w = y[p * 4 + 3];
      *((float4*)yp + p * 256 + t) = o;
    }
    return;
  }

  amax = wred_max(amax);
  if (lane == 0) redm[wid] = amax;
  __syncthreads();
  const float bmax = fmaxf(fmaxf(redm[0], redm[1]), fmaxf(redm[2], redm[3]));
  const float sval = fmaxf(bmax / 448.0f, 1e-10f);  // ref: max|y|/448, floor 1e-10

  u32* qp = (u32*)(qout + (size_t)row * HH);
#pragma unroll
  for (int p = 0; p < 4; ++p) {
    float q0 = fminf(fmaxf(y[p * 4 + 0] / sval, -448.f), 448.f);
    float q1 = fminf(fmaxf(y[p * 4 + 1] / sval, -448.f), 448.f);
    float q2 = fminf(fmaxf(y[p * 4 + 2] / sval, -448.f), 448.f);
    float q3 = fminf(fmaxf(y[p * 4 + 3] / sval, -448.f), 448.f);
    qp[p * 256 + t] = cvt4_fp8(q0, q1, q2, q3);
  }
  if (t == 0) sout[row] = sval;
}

// ---- fp8 GEMM via MX-scaled MFMA (unit scales => exact fp8 matmul at 2x rate)
// C[t,j] = sum_k Aq[t,k]*Bq[j,k]; resid[t,j] += C*s[t]*wsc[j]
// R18 = R17 shell + REGISTER FRAGMENT READ-AHEAD (targets the diagnosed
// ds_read->MFMA dependency-latency limiter: per-wave serial chain was
// 8 reads (~96cy issue) + ~120cy latency + 275cy MFMA; now tile j+1's reads
// issue BEFORE tile j's MFMA burst and complete under it).
// Structure: 4-buffer LDS ring (64KB, 2 blocks/CU), staging depth 3
// (stage j+3 each body), loop unrolled x2 with STATIC register sets
// (av0/bv0, av1/bv1 - no runtime indexing, rule #20).
// Body computing tile j: { stage j+3 -> buf[(j+3)&3]; ds_read frags of j+1
// from buf[(j+1)&3] into other set; MFMA j from current set; vmcnt; barrier }.
// vmcnt ledger: in-flight at wait = stages of j+2 (4, staged in body j-1)
// + j+3 (4, this body) = 8 -> vmcnt(4) ensures j+2 (FIFO). Tail: when
// j+3>=NT and j+2<NT -> vmcnt(0); when j+2>=NT -> none needed.
// Read-validity: frags of j+1 read in body j require tile j+1 LDS-landed:
// ensured by body j-1's vmcnt(4) (ensured (j-1)+2 = j+1) + barrier. Prologue
// ensures tile 0 (vmcnt(8)) and tile 1 (body -:  stage t0,t1,t2 then
// vmcnt(8) covers t0; body 0's reads of t1 covered since body "-1" ensure =
// prologue vmcnt(8) leaves t1,t2 flying -> NOT ensured! Fix: prologue uses
// vmcnt(4) (t0 AND t1 landed; t2 flying).
// Write-safety: body j stages into buf[(j+3)&3] = buf[(j-1)&3]; tile j-1's
// fragments were read during body j-2, two barriers before. Safe.
// Shell (verified R10/R17): 128x128 tile, 4 waves (2x2), 2x2 frags of
// 32x32x64; swizzle cb ^= (r>>1)&3 both-sides; grouped XCD swizzle (4MB L2
// set); setprio(1) on MFMA cluster.
// Frag layout (32x32x64 f8f6f4): lane l -> row/col = l&31, k = (l>>5)*32+byte.
// C/D: col=lane&31, row=(reg&3)+8*(reg>>2)+4*(lane>>5)  [HW-verified m74/m101].
__global__ __launch_bounds__(256) void kgemm(const u8* __restrict__ Aq,
                                             const u8* __restrict__ Bq,
                                             const float* __restrict__ srow,
                                             const float* __restrict__ wsc,
                                             float* __restrict__ resid) {
  constexpr int K = HH, N = HH;
  constexpr int NT = K / 64;  // 64 (even)
  __shared__ __align__(16) u8 smAf[4 * 128 * 64];  // 32 KiB
  __shared__ __align__(16) u8 smBf[4 * 128 * 64];  // 32 KiB

  // grouped 2-level swizzle (R10): 4x4 (tm,tn) groups per XCD -> 4 MB L2 set
  const int bidraw = blockIdx.x;
  const int xcd = bidraw & 7;
  const int c = bidraw >> 3;            // 0..511
  const int g = c >> 4;                 // 32 groups of 16 blocks
  const int gr = g >> 3, gc = g & 7;    // 4 x 8 grid of groups
  const int gm = (c >> 2) & 3, gn = c & 3;
  const int tm = xcd * 16 + gr * 4 + gm;  // 0..127
  const int tn = gc * 4 + gn;             // 0..31
  const int row0 = tm * 128, col0 = tn * 128;

  const int t = threadIdx.x;
  const int lane = t & 63, wid = t >> 6;
  const int wr = wid >> 1, wc = wid & 1;
  const int rl32 = lane & 31, hi = lane >> 5;

  f32x16 acc[2][2];
#pragma unroll
  for (int m = 0; m < 2; ++m)
#pragma unroll
    for (int n = 0; n < 2; ++n) acc[m][n] = (f32x16)0.f;

  // staging addresses: thread t covers LDS bytes [off, off+16) of each 8KB buffer
  int aoffg[2], boffg[2], ldso[2];
#pragma unroll
  for (int p = 0; p < 2; ++p) {
    const int off = (wid * 2 + p) * 1024 + lane * 16;
    const int r = off >> 6;
    const int cb = ((off >> 4) & 3) ^ ((r >> 1) & 3);  // inverse-swizzled source block
    aoffg[p] = (row0 + r) * K + cb * 16;
    boffg[p] = (col0 + r) * K + cb * 16;
    ldso[p] = off;
  }

  // fragment read offsets within a buffer
  int aro[2][2], bro[2][2];
#pragma unroll
  for (int m = 0; m < 2; ++m) {
    const int r = wr * 64 + m * 32 + rl32;
    const int swz = (r >> 1) & 3;
    aro[m][0] = r * 64 + ((hi * 2) ^ swz) * 16;
    aro[m][1] = r * 64 + ((hi * 2 + 1) ^ swz) * 16;
  }
#pragma unroll
  for (int n = 0; n < 2; ++n) {
    const int r = wc * 64 + n * 32 + rl32;
    const int swz = (r >> 1) & 3;
    bro[n][0] = r * 64 + ((hi * 2) ^ swz) * 16;
    bro[n][1] = r * 64 + ((hi * 2 + 1) ^ swz) * 16;
  }

  // prologue: stage tiles 0,1,2 into bufs 0,1,2 (12 loads)
#pragma unroll
  for (int p = 0; p < 2; ++p) {
    gl_lds16(Aq + aoffg[p], smAf + ldso[p]);
    gl_lds16(Bq + boffg[p], smBf + ldso[p]);
  }
#pragma unroll
  for (int p = 0; p < 2; ++p) {
    gl_lds16(Aq + aoffg[p] + 64, smAf + 8192 + ldso[p]);
    gl_lds16(Bq + boffg[p] + 64, smBf + 8192 + ldso[p]);
  }
#pragma unroll
  for (int p = 0; p < 2; ++p) {
    gl_lds16(Aq + aoffg[p] + 128, smAf + 16384 + ldso[p]);
    gl_lds16(Bq + boffg[p] + 128, smBf + 16384 + ldso[p]);
  }
  asm volatile("s_waitcnt vmcnt(4)" ::: "memory");  // tiles 0,1 landed; 2 flying
  __builtin_amdgcn_s_barrier();
  __builtin_amdgcn_sched_barrier(0);

  // pre-read tile 0 fragments into set0
  i32x8 av0[2], bv0[2], av1[2], bv1[2];
#pragma unroll
  for (int m = 0; m < 2; ++m) av0[m] = ld32B(smAf + aro[m][0], smAf + aro[m][1]);
#pragma unroll
  for (int n = 0; n < 2; ++n) bv0[n] = ld32B(smBf + bro[n][0], smBf + bro[n][1]);

  for (int it = 0; it < NT; it += 2) {
    // ---- body A: compute tile it (set0); read it+1 -> set1; stage it+3 ----
    {
      const int j = it;
      if (j + 3 < NT) {
        const size_t ko = (size_t)(j + 3) * 64;
        u8* dA = smAf + ((j + 3) & 3) * 8192;
        u8* dB = smBf + ((j + 3) & 3) * 8192;
#pragma unroll
        for (int p = 0; p < 2; ++p) {
          gl_lds16(Aq + aoffg[p] + ko, dA + ldso[p]);
          gl_lds16(Bq + boffg[p] + ko, dB + ldso[p]);
        }
      }
      if (j + 1 < NT) {
        const u8* sA = smAf + ((j + 1) & 3) * 8192;
        const u8* sB = smBf + ((j + 1) & 3) * 8192;
#pragma unroll
        for (int m = 0; m < 2; ++m) av1[m] = ld32B(sA + aro[m][0], sA + aro[m][1]);
#pragma unroll
        for (int n = 0; n < 2; ++n) bv1[n] = ld32B(sB + bro[n][0], sB + bro[n][1]);
      }
      __builtin_amdgcn_s_setprio(1);
#pragma unroll
      for (int m = 0; m < 2; ++m)
#pragma unroll
        for (int n = 0; n < 2; ++n)
          acc[m][n] = __builtin_amdgcn_mfma_scale_f32_32x32x64_f8f6f4(
              av0[m], bv0[n], acc[m][n], 0 /*A=fp8*/, 0 /*B=fp8*/,
              0, 0x7f7f7f7f, 0, 0x7f7f7f7f);  // e8m0 127 = 2^0 = exact
      __builtin_amdgcn_s_setprio(0);
      if (j + 3 < NT) {
        asm volatile("s_waitcnt vmcnt(4)" ::: "memory");  // tile j+2 landed
      } else if (j + 2 < NT) {
        asm volatile("s_waitcnt vmcnt(0)" ::: "memory");
      }
      __builtin_amdgcn_sched_barrier(0);
      __builtin_amdgcn_s_barrier();
      __builtin_amdgcn_sched_barrier(0);
    }
    // ---- body B: compute tile it+1 (set1); read it+2 -> set0; stage it+4 ----
    {
      const int j = it + 1;
      if (j + 3 < NT) {
        const size_t ko = (size_t)(j + 3) * 64;
        u8* dA = smAf + ((j + 3) & 3) * 8192;
        u8* dB = smBf + ((j + 3) & 3) * 8192;
#pragma unroll
        for (int p = 0; p < 2; ++p) {
          gl_lds16(Aq + aoffg[p] + ko, dA + ldso[p]);
          gl_lds16(Bq + boffg[p] + ko, dB + ldso[p]);
        }
      }
      if (j + 1 < NT) {
        const u8* sA = smAf + ((j + 1) & 3) * 8192;
        const u8* sB = smBf + ((j + 1) & 3) * 8192;
#pragma unroll
        for (int m = 0; m < 2; ++m) av0[m] = ld32B(sA + aro[m][0], sA + aro[m][1]);
#pragma unroll
        for (int n = 0; n < 2; ++n) bv0[n] = ld32B(sB + bro[n][0], sB + bro[n][1]);
      }
      __builtin_amdgcn_s_setprio(1);
#pragma unroll
      for (int m = 0; m < 2; ++m)
#pragma unroll
        for (int n = 0; n < 2; ++n)
          acc[m][n] = __builtin_amdgcn_mfma_scale_f32_32x32x64_f8f6f4(
              av1[m], bv1[n], acc[m][n], 0, 0, 0, 0x7f7f7f7f, 0, 0x7f7f7f7f);
      __builtin_amdgcn_s_setprio(0);
      if (j + 3 < NT) {
        asm volatile("s_waitcnt vmcnt(4)" ::: "memory");  // tile j+2 landed
      } else if (j + 2 < NT) {
        asm volatile("s_waitcnt vmcnt(0)" ::: "memory");
      }
      __builtin_amdgcn_sched_barrier(0);
      __builtin_amdgcn_s_barrier();
      __builtin_amdgcn_sched_barrier(0);
    }
  }

  // epilogue: resid += (acc * s_token) * wscale_col
  const int cc = rl32;
  const int rb = hi * 4;
  float wvv[2];
#pragma unroll
  for (int n = 0; n < 2; ++n) wvv[n] = wsc[col0 + wc * 64 + n * 32 + cc];
#pragma unroll
  for (int m = 0; m < 2; ++m) {
#pragma unroll
    for (int g2 = 0; g2 < 4; ++g2) {
#pragma unroll
      for (int j = 0; j < 4; ++j) {
        const int row = row0 + wr * 64 + m * 32 + g2 * 8 + rb + j;
        const float sv = srow[row];
#pragma unroll
        for (int n = 0; n < 2; ++n) {
          const int col = col0 + wc * 64 + n * 32 + cc;
          const size_t idx = (size_t)row * N + col;
          resid[idx] = resid[idx] + (acc[m][n][g2 * 4 + j] * sv) * wvv[n];
        }
      }
    }
  }
}

extern "C" void kernel_launch(void* const* d_in, const int* in_sizes, int n_in,
                              void* d_out, int out_size, void* d_ws, size_t ws_size,
                              hipStream_t stream) {
  const float* x   = (const float*)d_in[0];
  const float* nw0 = (const float*)d_in[1];
  const float* nw1 = (const float*)d_in[2];
  const float* nw2 = (const float*)d_in[3];
  const float* w0  = (const float*)d_in[4];
  const float* w1  = (const float*)d_in[5];
  const float* ws0 = (const float*)d_in[6];
  const float* ws1 = (const float*)d_in[7];
  float* out = (float*)d_out;

  // workspace: q (T*H fp8) | w0q (H*H fp8) | w1q (H*H fp8) | s (T fp32)  ~= 96.1 MiB
  u8* q = (u8*)d_ws;
  u8* w0q = q + (size_t)TT * HH;
  u8* w1q = w0q + (size_t)HH * HH;
  float* sbuf = (float*)(w1q + (size_t)HH * HH);

  dim3 wg(HH / 64, HH / 64);
  kwquant<<<wg, 256, 0, stream>>>(w0, w0q);
  kwquant<<<wg, 256, 0, stream>>>(w1, w1q);

  knorm<0><<<TT, 256, 0, stream>>>(x, nw0, out, q, sbuf, nullptr);
  kgemm<<<(TT / 128) * (HH / 128), 256, 0, stream>>>(q, w0q, sbuf, ws0, out);
  knorm<1><<<TT, 256, 0, stream>>>(out, nw1, nullptr, q, sbuf, nullptr);
  kgemm<<<(TT / 128) * (HH / 128), 256, 0, stream>>>(q, w1q, sbuf, ws1, out);
  knorm<2><<<TT, 256, 0, stream>>>(out, nw2, nullptr, nullptr, nullptr, out);
}

// Round 19
// 1044.166 us; speedup vs baseline: 1.1622x; 1.1622x over previous
//
#include <hip/hip_runtime.h>
#include <stdint.h>

#define TT 16384
#define HH 4096

typedef uint8_t u8;
typedef uint32_t u32;
typedef __attribute__((ext_vector_type(16))) float f32x16;
typedef __attribute__((ext_vector_type(8))) int i32x8;

// ---- fp8 e4m3 (OCP) pack: 4 floats -> 4 bytes, RNE, saturating ----
__device__ __forceinline__ u32 cvt4_fp8(float a, float b, float c, float d) {
  u32 v = 0;
  v = __builtin_amdgcn_cvt_pk_fp8_f32(a, b, v, false);  // low word
  v = __builtin_amdgcn_cvt_pk_fp8_f32(c, d, v, true);   // high word
  return v;
}

__device__ __forceinline__ void gl_lds16(const void* g, void* l) {
  __builtin_amdgcn_global_load_lds(
      (const __attribute__((address_space(1))) void*)g,
      (__attribute__((address_space(3))) void*)l, 16, 0, 0);
}

__device__ __forceinline__ i32x8 ld32B(const u8* p0, const u8* p1) {
  const uint4 a = *(const uint4*)p0;
  const uint4 b = *(const uint4*)p1;
  i32x8 r;
  r[0] = (int)a.x; r[1] = (int)a.y; r[2] = (int)a.z; r[3] = (int)a.w;
  r[4] = (int)b.x; r[5] = (int)b.y; r[6] = (int)b.z; r[7] = (int)b.w;
  return r;
}

// ---- weight quantize + transpose: w[K][N] fp32 (on fp8 grid) -> wq[N][K] fp8 (plain)
__global__ __launch_bounds__(256) void kwquant(const float* __restrict__ w,
                                               u8* __restrict__ wq) {
  __shared__ __align__(16) u8 tile[64][68];
  const int n0 = blockIdx.x * 64;
  const int k0 = blockIdx.y * 64;
  const int t = threadIdx.x;
  const int tr = t >> 4, tc = t & 15;
#pragma unroll
  for (int p = 0; p < 4; ++p) {
    const int kl = p * 16 + tr;
    const float4 v = *(const float4*)(w + (size_t)(k0 + kl) * HH + n0 + tc * 4);
    const u32 pk = cvt4_fp8(v.x, v.y, v.z, v.w);
    tile[tc * 4 + 0][kl] = (u8)(pk);
    tile[tc * 4 + 1][kl] = (u8)(pk >> 8);
    tile[tc * 4 + 2][kl] = (u8)(pk >> 16);
    tile[tc * 4 + 3][kl] = (u8)(pk >> 24);
  }
  __syncthreads();
  const int jr = t >> 2;
  const int kc = (t & 3) * 16;
  uint4 ov;
  ov.x = *(const u32*)&tile[jr][kc + 0];
  ov.y = *(const u32*)&tile[jr][kc + 4];
  ov.z = *(const u32*)&tile[jr][kc + 8];
  ov.w = *(const u32*)&tile[jr][kc + 12];
  *(uint4*)(wq + (size_t)(n0 + jr) * HH + k0 + kc) = ov;
}

__device__ __forceinline__ float wred_sum(float v) {
#pragma unroll
  for (int o = 32; o; o >>= 1) v += __shfl_down(v, o, 64);
  return v;
}
__device__ __forceinline__ float wred_max(float v) {
#pragma unroll
  for (int o = 32; o; o >>= 1) v = fmaxf(v, __shfl_down(v, o, 64));
  return v;
}

// MODE 0: src=x, write resid=sqrt(x), quantize rmsnorm(x,nw) -> qout,sout
// MODE 1: src=resid, quantize rmsnorm(resid,nw) -> qout,sout
// MODE 2: src=resid, write y=rmsnorm(resid,nw) fp32 -> yout
template <int MODE>
__global__ __launch_bounds__(256) void knorm(const float* __restrict__ src,
                                             const float* __restrict__ nw,
                                             float* __restrict__ resid_out,
                                             u8* __restrict__ qout,
                                             float* __restrict__ sout,
                                             float* __restrict__ yout) {
  __shared__ float red[4];
  __shared__ float redm[4];
  const int row = blockIdx.x;
  const int t = threadIdx.x;
  const int lane = t & 63, wid = t >> 6;
  const float* rp = src + (size_t)row * HH;

  float4 xv[4];
  float ssq = 0.f;
#pragma unroll
  for (int p = 0; p < 4; ++p) {
    xv[p] = *((const float4*)rp + p * 256 + t);
    ssq += xv[p].x * xv[p].x;
    ssq += xv[p].y * xv[p].y;
    ssq += xv[p].z * xv[p].z;
    ssq += xv[p].w * xv[p].w;
  }
  if (MODE == 0) {
    float* rr = resid_out + (size_t)row * HH;
#pragma unroll
    for (int p = 0; p < 4; ++p) {
      float4 r4;
      r4.x = sqrtf(xv[p].x); r4.y = sqrtf(xv[p].y);
      r4.z = sqrtf(xv[p].z); r4.w = sqrtf(xv[p].w);
      *((float4*)rr + p * 256 + t) = r4;
    }
  }
  ssq = wred_sum(ssq);
  if (lane == 0) red[wid] = ssq;
  __syncthreads();
  const float ms = (((red[0] + red[1]) + red[2]) + red[3]) * (1.0f / HH);
  const float inv = 1.0f / sqrtf(ms + 1e-6f);

  float y[16];
  float amax = 0.f;
#pragma unroll
  for (int p = 0; p < 4; ++p) {
    const float4 wv = *((const float4*)nw + p * 256 + t);
    y[p * 4 + 0] = (xv[p].x * inv) * wv.x;
    y[p * 4 + 1] = (xv[p].y * inv) * wv.y;
    y[p * 4 + 2] = (xv[p].z * inv) * wv.z;
    y[p * 4 + 3] = (xv[p].w * inv) * wv.w;
    amax = fmaxf(amax, fabsf(y[p * 4 + 0]));
    amax = fmaxf(amax, fabsf(y[p * 4 + 1]));
    amax = fmaxf(amax, fabsf(y[p * 4 + 2]));
    amax = fmaxf(amax, fabsf(y[p * 4 + 3]));
  }

  if (MODE == 2) {
    float* yp = yout + (size_t)row * HH;
#pragma unroll
    for (int p = 0; p < 4; ++p) {
      float4 o;
      o.x = y[p * 4 + 0]; o.y = y[p * 4 + 1];
      o.z = y[p * 4 + 2]; o.w = y[p * 4 + 3];
      *((float4*)yp + p * 256 + t) = o;
    }
    return;
  }

  amax = wred_max(amax);
  if (lane == 0) redm[wid] = amax;
  __syncthreads();
  const float bmax = fmaxf(fmaxf(redm[0], redm[1]), fmaxf(redm[2], redm[3]));
  const float sval = fmaxf(bmax / 448.0f, 1e-10f);  // ref: max|y|/448, floor 1e-10

  u32* qp = (u32*)(qout + (size_t)row * HH);
#pragma unroll
  for (int p = 0; p < 4; ++p) {
    float q0 = fminf(fmaxf(y[p * 4 + 0] / sval, -448.f), 448.f);
    float q1 = fminf(fmaxf(y[p * 4 + 1] / sval, -448.f), 448.f);
    float q2 = fminf(fmaxf(y[p * 4 + 2] / sval, -448.f), 448.f);
    float q3 = fminf(fmaxf(y[p * 4 + 3] / sval, -448.f), 448.f);
    qp[p * 256 + t] = cvt4_fp8(q0, q1, q2, q3);
  }
  if (t == 0) sout[row] = sval;
}

// ---- fp8 GEMM via MX-scaled MFMA (unit scales => exact fp8 matmul at 2x rate)
// C[t,j] = sum_k Aq[t,k]*Bq[j,k]; resid[t,j] += C*s[t]*wsc[j]
// FINAL (R10, session best: kgemm 422us, total 1045us):
// 128x128 tile, BK=64, 4 waves (2x2), wave 2x2 frags of 32x32x64;
// 3 LDS buffers (48 KiB, ~3 blocks/CU) prefetch-2, vmcnt(8/4/0) cascade;
// 16B-block swizzle cb ^= (r>>1)&3 both-sides (measured best of 3 variants);
// grouped XCD swizzle: 4x4 (tm,tn) groups per XCD -> 4MB working set resident
// in the per-XCD L2 (FETCH 0.66->0.46 GB measured); setprio(1) on MFMAs.
// Session-falsified alternatives (counters in journal): 0-conflict K-perm
// layout (R5), 256²/64KB (R8), A-in-VGPR (R11/R15), m201-style phases
// (R12/R14), 2-wave blocks (R16), single-barrier (R17), frag read-ahead
// (R18) — plateau is 2-phase-structural (matches m230/m233), not pipe-bound.
// Frag layout (32x32x64 f8f6f4): lane l -> row/col = l&31, k = (l>>5)*32+byte.
// C/D: col=lane&31, row=(reg&3)+8*(reg>>2)+4*(lane>>5)  [HW-verified m74/m101].
__global__ __launch_bounds__(256) void kgemm(const u8* __restrict__ Aq,
                                             const u8* __restrict__ Bq,
                                             const float* __restrict__ srow,
                                             const float* __restrict__ wsc,
                                             float* __restrict__ resid) {
  constexpr int K = HH, N = HH;
  constexpr int NT = K / 64;
  __shared__ __align__(16) u8 smAf[3 * 128 * 64];  // 24 KiB
  __shared__ __align__(16) u8 smBf[3 * 128 * 64];  // 24 KiB

  // grouped 2-level swizzle: 4x4 (tm,tn) groups per XCD -> 4 MB L2 set
  const int bidraw = blockIdx.x;
  const int xcd = bidraw & 7;
  const int c = bidraw >> 3;            // 0..511
  const int g = c >> 4;                 // 32 groups of 16 blocks
  const int gr = g >> 3, gc = g & 7;    // 4 x 8 grid of groups
  const int gm = (c >> 2) & 3, gn = c & 3;
  const int tm = xcd * 16 + gr * 4 + gm;  // 0..127
  const int tn = gc * 4 + gn;             // 0..31
  const int row0 = tm * 128, col0 = tn * 128;

  const int t = threadIdx.x;
  const int lane = t & 63, wid = t >> 6;
  const int wr = wid >> 1, wc = wid & 1;
  const int rl32 = lane & 31, hi = lane >> 5;

  f32x16 acc[2][2];
#pragma unroll
  for (int m = 0; m < 2; ++m)
#pragma unroll
    for (int n = 0; n < 2; ++n) acc[m][n] = (f32x16)0.f;

  // staging addresses: thread t covers LDS bytes [off, off+16) of each 8KB buffer
  int aoffg[2], boffg[2], ldso[2];
#pragma unroll
  for (int p = 0; p < 2; ++p) {
    const int off = (wid * 2 + p) * 1024 + lane * 16;
    const int r = off >> 6;
    const int cb = ((off >> 4) & 3) ^ ((r >> 1) & 3);  // inverse-swizzled source block
    aoffg[p] = (row0 + r) * K + cb * 16;
    boffg[p] = (col0 + r) * K + cb * 16;
    ldso[p] = off;
  }

  // fragment read offsets within a buffer
  int aro[2][2], bro[2][2];
#pragma unroll
  for (int m = 0; m < 2; ++m) {
    const int r = wr * 64 + m * 32 + rl32;
    const int swz = (r >> 1) & 3;
    aro[m][0] = r * 64 + ((hi * 2) ^ swz) * 16;
    aro[m][1] = r * 64 + ((hi * 2 + 1) ^ swz) * 16;
  }
#pragma unroll
  for (int n = 0; n < 2; ++n) {
    const int r = wc * 64 + n * 32 + rl32;
    const int swz = (r >> 1) & 3;
    bro[n][0] = r * 64 + ((hi * 2) ^ swz) * 16;
    bro[n][1] = r * 64 + ((hi * 2 + 1) ^ swz) * 16;
  }

  // prologue: stage tile 0 (buf 0) then tile 1 (buf 1) — 4 loads each
#pragma unroll
  for (int p = 0; p < 2; ++p) {
    gl_lds16(Aq + aoffg[p], smAf + ldso[p]);
    gl_lds16(Bq + boffg[p], smBf + ldso[p]);
  }
#pragma unroll
  for (int p = 0; p < 2; ++p) {
    gl_lds16(Aq + aoffg[p] + 64, smAf + 8192 + ldso[p]);
    gl_lds16(Bq + boffg[p] + 64, smBf + 8192 + ldso[p]);
  }

  int bc = 0;  // compute buffer = it % 3
  int bs = 2;  // stage buffer = (it+2) % 3
  for (int it = 0; it < NT; ++it) {
    if (it + 2 < NT) {
      const size_t ko = (size_t)(it + 2) * 64;
      u8* dA = smAf + bs * 8192;
      u8* dB = smBf + bs * 8192;
#pragma unroll
      for (int p = 0; p < 2; ++p) {
        gl_lds16(Aq + aoffg[p] + ko, dA + ldso[p]);
        gl_lds16(Bq + boffg[p] + ko, dB + ldso[p]);
      }
      asm volatile("s_waitcnt vmcnt(8)" ::: "memory");  // tile it landed; it+1,it+2 in flight
    } else if (it + 1 < NT) {
      asm volatile("s_waitcnt vmcnt(4)" ::: "memory");
    } else {
      asm volatile("s_waitcnt vmcnt(0)" ::: "memory");
    }
    __builtin_amdgcn_s_barrier();
    __builtin_amdgcn_sched_barrier(0);

    const u8* sA = smAf + bc * 8192;
    const u8* sB = smBf + bc * 8192;
    i32x8 av[2], bv[2];
#pragma unroll
    for (int m = 0; m < 2; ++m) av[m] = ld32B(sA + aro[m][0], sA + aro[m][1]);
#pragma unroll
    for (int n = 0; n < 2; ++n) bv[n] = ld32B(sB + bro[n][0], sB + bro[n][1]);
    __builtin_amdgcn_s_setprio(1);
#pragma unroll
    for (int m = 0; m < 2; ++m)
#pragma unroll
      for (int n = 0; n < 2; ++n)
        acc[m][n] = __builtin_amdgcn_mfma_scale_f32_32x32x64_f8f6f4(
            av[m], bv[n], acc[m][n], 0 /*A=fp8*/, 0 /*B=fp8*/,
            0, 0x7f7f7f7f, 0, 0x7f7f7f7f);  // e8m0 127 = 2^0 = exact
    __builtin_amdgcn_s_setprio(0);
    __builtin_amdgcn_sched_barrier(0);
    __builtin_amdgcn_s_barrier();
    bc = (bc == 2) ? 0 : bc + 1;
    bs = (bs == 2) ? 0 : bs + 1;
  }

  // epilogue: resid += (acc * s_token) * wscale_col
  const int cc = rl32;
  const int rb = hi * 4;
  float wvv[2];
#pragma unroll
  for (int n = 0; n < 2; ++n) wvv[n] = wsc[col0 + wc * 64 + n * 32 + cc];
#pragma unroll
  for (int m = 0; m < 2; ++m) {
#pragma unroll
    for (int g2 = 0; g2 < 4; ++g2) {
#pragma unroll
      for (int j = 0; j < 4; ++j) {
        const int row = row0 + wr * 64 + m * 32 + g2 * 8 + rb + j;
        const float sv = srow[row];
#pragma unroll
        for (int n = 0; n < 2; ++n) {
          const int col = col0 + wc * 64 + n * 32 + cc;
          const size_t idx = (size_t)row * N + col;
          resid[idx] = resid[idx] + (acc[m][n][g2 * 4 + j] * sv) * wvv[n];
        }
      }
    }
  }
}

extern "C" void kernel_launch(void* const* d_in, const int* in_sizes, int n_in,
                              void* d_out, int out_size, void* d_ws, size_t ws_size,
                              hipStream_t stream) {
  const float* x   = (const float*)d_in[0];
  const float* nw0 = (const float*)d_in[1];
  const float* nw1 = (const float*)d_in[2];
  const float* nw2 = (const float*)d_in[3];
  const float* w0  = (const float*)d_in[4];
  const float* w1  = (const float*)d_in[5];
  const float* ws0 = (const float*)d_in[6];
  const float* ws1 = (const float*)d_in[7];
  float* out = (float*)d_out;

  // workspace: q (T*H fp8) | w0q (H*H fp8) | w1q (H*H fp8) | s (T fp32)  ~= 96.1 MiB
  u8* q = (u8*)d_ws;
  u8* w0q = q + (size_t)TT * HH;
  u8* w1q = w0q + (size_t)HH * HH;
  float* sbuf = (float*)(w1q + (size_t)HH * HH);

  dim3 wg(HH / 64, HH / 64);
  kwquant<<<wg, 256, 0, stream>>>(w0, w0q);
  kwquant<<<wg, 256, 0, stream>>>(w1, w1q);

  knorm<0><<<TT, 256, 0, stream>>>(x, nw0, out, q, sbuf, nullptr);
  kgemm<<<(TT / 128) * (HH / 128), 256, 0, stream>>>(q, w0q, sbuf, ws0, out);
  knorm<1><<<TT, 256, 0, stream>>>(out, nw1, nullptr, q, sbuf, nullptr);
  kgemm<<<(TT / 128) * (HH / 128), 256, 0, stream>>>(q, w1q, sbuf, ws1, out);
  knorm<2><<<TT, 256, 0, stream>>>(out, nw2, nullptr, nullptr, nullptr, out);
}